// Round 11
// baseline (267.605 us; speedup 1.0000x reference)
//
#include <hip/hip_runtime.h>
#include <math.h>

// ---------------------------------------------------------------------------
// MambaCaMix on MI355X — round 11: R8 baseline (best, 254.6us) + two safe
// dispatch removals: att fused into final (R10-proven), ysum zero-fill folded
// into k_proj. Hot kernels byte-identical to R8. 11 dispatches (was 13).
// Lessons encoded: never fuse parallel work into low-occupancy MFMA kernels
// (R7/R10); no high-frequency same-line atomics (R7); coop launch fails (R4).
// B=2, Cin=64, C=128, H=W=64 (L=4096), D_INNER=256, N_STATE=16, DT_RANK=8, K=4
// ---------------------------------------------------------------------------

#define DEV __device__ __forceinline__

typedef __attribute__((ext_vector_type(8))) short bf16x8;
typedef __attribute__((ext_vector_type(4))) float f32x4;

DEV float sigm_(float x){ return 1.f/(1.f+__expf(-x)); }
DEV float silu_(float x){ return x*sigm_(x); }
DEV float sp_(float x){ return (x>15.f)? x : __logf(1.f+__expf(x)); }

DEV unsigned short f2bf(float f){
  union{float f; unsigned u;} v; v.f=f;
  unsigned r=v.u + 0x7FFFu + ((v.u>>16)&1u);
  return (unsigned short)(r>>16);
}
DEV float bf2f(unsigned short h){ union{unsigned u; float f;} v; v.u=((unsigned)h)<<16; return v.f; }

DEV int pos_dir(int k, int l){
  switch(k&3){
    case 0: return l;
    case 1: return ((l&63)<<6)|(l>>6);
    case 2: return 4095-l;
    default:{ int m=4095-l; return ((m&63)<<6)|(m>>6); }
  }
}

DEV bf16x8 cvt_frag(const float* p){
  float4 q0=*(const float4*)p, q1=*(const float4*)(p+4);
  bf16x8 t;
  t[0]=(short)f2bf(q0.x); t[1]=(short)f2bf(q0.y); t[2]=(short)f2bf(q0.z); t[3]=(short)f2bf(q0.w);
  t[4]=(short)f2bf(q1.x); t[5]=(short)f2bf(q1.y); t[6]=(short)f2bf(q1.z); t[7]=(short)f2bf(q1.w);
  return t;
}

// K1: fused 1x1 conv-in + LayerNorm(128). Writes x1 (B,C,L) f32, mln bf16 (B*L,128).
__global__ __launch_bounds__(256) void k_x1ln(const float* __restrict__ x,
    const float* __restrict__ W, const float* __restrict__ bias,
    const float* __restrict__ g, const float* __restrict__ be,
    float* __restrict__ x1, unsigned short* __restrict__ mlnb){
  const int b=blockIdx.y, p0=blockIdx.x*64;
  __shared__ float sw[64*132];
  __shared__ float sx[64*68];
  __shared__ float red[2][16][68];
  __shared__ float smu[64], srs[64];
  const int tid=threadIdx.x, tx=tid&15, ty=tid>>4;
  for (int i=tid;i<8192;i+=256){ int c=i&63,o=i>>6; sw[c*132+o]=W[o*64+c]; }
  for (int i=tid;i<4096;i+=256){ int c=i>>6,p=i&63; sx[c*68+p]=x[((size_t)(b*64+c))*4096+p0+p]; }
  __syncthreads();
  float acc[8][4]={};
  for (int c=0;c<64;++c){
    float4 a0=*(const float4*)&sw[c*132+ty*8];
    float4 a1=*(const float4*)&sw[c*132+ty*8+4];
    float4 bv=*(const float4*)&sx[c*68+tx*4];
    acc[0][0]=fmaf(a0.x,bv.x,acc[0][0]); acc[0][1]=fmaf(a0.x,bv.y,acc[0][1]); acc[0][2]=fmaf(a0.x,bv.z,acc[0][2]); acc[0][3]=fmaf(a0.x,bv.w,acc[0][3]);
    acc[1][0]=fmaf(a0.y,bv.x,acc[1][0]); acc[1][1]=fmaf(a0.y,bv.y,acc[1][1]); acc[1][2]=fmaf(a0.y,bv.z,acc[1][2]); acc[1][3]=fmaf(a0.y,bv.w,acc[1][3]);
    acc[2][0]=fmaf(a0.z,bv.x,acc[2][0]); acc[2][1]=fmaf(a0.z,bv.y,acc[2][1]); acc[2][2]=fmaf(a0.z,bv.z,acc[2][2]); acc[2][3]=fmaf(a0.z,bv.w,acc[2][3]);
    acc[3][0]=fmaf(a0.w,bv.x,acc[3][0]); acc[3][1]=fmaf(a0.w,bv.y,acc[3][1]); acc[3][2]=fmaf(a0.w,bv.z,acc[3][2]); acc[3][3]=fmaf(a0.w,bv.w,acc[3][3]);
    acc[4][0]=fmaf(a1.x,bv.x,acc[4][0]); acc[4][1]=fmaf(a1.x,bv.y,acc[4][1]); acc[4][2]=fmaf(a1.x,bv.z,acc[4][2]); acc[4][3]=fmaf(a1.x,bv.w,acc[4][3]);
    acc[5][0]=fmaf(a1.y,bv.x,acc[5][0]); acc[5][1]=fmaf(a1.y,bv.y,acc[5][1]); acc[5][2]=fmaf(a1.y,bv.z,acc[5][2]); acc[5][3]=fmaf(a1.y,bv.w,acc[5][3]);
    acc[6][0]=fmaf(a1.z,bv.x,acc[6][0]); acc[6][1]=fmaf(a1.z,bv.y,acc[6][1]); acc[6][2]=fmaf(a1.z,bv.z,acc[6][2]); acc[6][3]=fmaf(a1.z,bv.w,acc[6][3]);
    acc[7][0]=fmaf(a1.w,bv.x,acc[7][0]); acc[7][1]=fmaf(a1.w,bv.y,acc[7][1]); acc[7][2]=fmaf(a1.w,bv.z,acc[7][2]); acc[7][3]=fmaf(a1.w,bv.w,acc[7][3]);
  }
  float xr[8][4];
  #pragma unroll
  for (int i=0;i<8;++i){
    float bs=bias[ty*8+i];
    #pragma unroll
    for (int j=0;j<4;++j) xr[i][j]=acc[i][j]+bs;
  }
  {
    float s[4]={},s2[4]={};
    #pragma unroll
    for (int i=0;i<8;++i)
      #pragma unroll
      for (int j=0;j<4;++j){ s[j]+=xr[i][j]; s2[j]=fmaf(xr[i][j],xr[i][j],s2[j]); }
    #pragma unroll
    for (int j=0;j<4;++j){ red[0][ty][tx*4+j]=s[j]; red[1][ty][tx*4+j]=s2[j]; }
  }
  __syncthreads();
  if (tid<64){
    float S=0.f,S2=0.f;
    #pragma unroll
    for (int t=0;t<16;++t){ S+=red[0][t][tid]; S2+=red[1][t][tid]; }
    float mu=S*(1.f/128.f), var=S2*(1.f/128.f)-mu*mu;
    smu[tid]=mu; srs[tid]=rsqrtf(var+1e-5f);
  }
  __syncthreads();
  float* lnt=sw;
  #pragma unroll
  for (int i=0;i<8;++i){
    int o=ty*8+i;
    float gv=g[o], bev=be[o];
    #pragma unroll
    for (int j=0;j<4;++j){
      int p=tx*4+j;
      lnt[o*66+p]=(xr[i][j]-smu[p])*srs[p]*gv+bev;
    }
    *(float4*)&x1[((size_t)(b*128+o))*4096+p0+tx*4]=make_float4(xr[i][0],xr[i][1],xr[i][2],xr[i][3]);
  }
  __syncthreads();
  for (int i=tid;i<8192;i+=256){ int p=i>>7,o=i&127; mlnb[((size_t)(b*4096+p0+p))*128+o]=f2bf(lnt[o*66+p]); }
}

// K3: inproj MFMA. M=8192, N=512, K=128. cols<256 -> xmpre bf16; cols>=256 -> z f32.
__global__ __launch_bounds__(256) void k_inproj(const unsigned short* __restrict__ mlnb,
    const float* __restrict__ W, unsigned short* __restrict__ xmpreb, float* __restrict__ z){
  const int wave=threadIdx.x>>6, lane=threadIdx.x&63;
  const int quad=lane>>4, l16=lane&15;
  const int m0=blockIdx.y*128+(wave>>1)*64;
  const int n0=blockIdx.x*64+(wave&1)*32;
  f32x4 acc[4][2];
  #pragma unroll
  for (int i=0;i<4;++i)
    #pragma unroll
    for (int j=0;j<2;++j) acc[i][j]=(f32x4){0.f,0.f,0.f,0.f};
  for (int k0=0;k0<128;k0+=32){
    bf16x8 a[4], b[2];
    #pragma unroll
    for (int mi=0;mi<4;++mi)
      a[mi]=*(const bf16x8*)&mlnb[(size_t)(m0+mi*16+l16)*128 + k0 + quad*8];
    #pragma unroll
    for (int ni=0;ni<2;++ni)
      b[ni]=cvt_frag(&W[(size_t)(n0+ni*16+l16)*128 + k0 + quad*8]);
    #pragma unroll
    for (int mi=0;mi<4;++mi)
      #pragma unroll
      for (int ni=0;ni<2;++ni)
        acc[mi][ni]=__builtin_amdgcn_mfma_f32_16x16x32_bf16(a[mi],b[ni],acc[mi][ni],0,0,0);
  }
  #pragma unroll
  for (int mi=0;mi<4;++mi)
    #pragma unroll
    for (int ni=0;ni<2;++ni)
      #pragma unroll
      for (int r=0;r<4;++r){
        const int row=m0+mi*16+quad*4+r;
        const int col=n0+ni*16+l16;
        float v=acc[mi][ni][r];
        if (col<256) xmpreb[(size_t)row*256+col]=f2bf(v);
        else         z[(size_t)row*256+(col-256)]=v;
      }
}

// K4: depthwise 3x3 conv + bias + SiLU, bf16 in -> bf16 out (B,L,256)
__global__ __launch_bounds__(256) void k_dwconv(const unsigned short* __restrict__ xmpreb,
    const float* __restrict__ cw, const float* __restrict__ cb, unsigned short* __restrict__ xflatb){
  __shared__ float sw[2304];
  __shared__ float sb[256];
  const int tid=threadIdx.x;
  for (int i=tid;i<2304;i+=256) sw[i]=cw[i];
  sb[tid]=cb[tid];
  __syncthreads();
  const int bp0=blockIdx.x*16;
  const int b=bp0>>12, p0=bp0&4095;
  const int dq=tid&63, pg=tid>>6;
  const int d0=dq*4;
  float wr[9][4];
  #pragma unroll
  for (int t=0;t<9;++t)
    #pragma unroll
    for (int c=0;c<4;++c) wr[t][c]=sw[(d0+c)*9+t];
  const float4 bias=make_float4(sb[d0],sb[d0+1],sb[d0+2],sb[d0+3]);
  #pragma unroll
  for (int j=0;j<4;++j){
    const int p=p0+pg*4+j;
    const int h=p>>6, w=p&63;
    float4 acc=bias;
    #pragma unroll
    for (int dh=-1;dh<=1;++dh){
      int hh=h+dh; if ((unsigned)hh>=64u) continue;
      #pragma unroll
      for (int dw=-1;dw<=1;++dw){
        int ww=w+dw; if ((unsigned)ww>=64u) continue;
        const int t=(dh+1)*3+(dw+1);
        ushort4 u4=*(const ushort4*)&xmpreb[((size_t)((b<<12)+hh*64+ww))*256+d0];
        acc.x=fmaf(bf2f(u4.x),wr[t][0],acc.x); acc.y=fmaf(bf2f(u4.y),wr[t][1],acc.y);
        acc.z=fmaf(bf2f(u4.z),wr[t][2],acc.z); acc.w=fmaf(bf2f(u4.w),wr[t][3],acc.w);
      }
    }
    ushort4 o;
    o.x=f2bf(silu_(acc.x)); o.y=f2bf(silu_(acc.y)); o.z=f2bf(silu_(acc.z)); o.w=f2bf(silu_(acc.w));
    *(ushort4*)&xflatb[((size_t)((b<<12)+p))*256+d0]=o;
  }
}

// K5: proj MFMA. M=160 (r), N=8192, K=256. 256 blocks x 32 cols.
// Prologue: zero this block's 32KB slice of ysum (replaces the memset dispatch;
// kernel-boundary ordering makes it visible to scanA).
__global__ __launch_bounds__(256) void k_proj(const unsigned short* __restrict__ xflatb,
    const float* __restrict__ xpw, float* __restrict__ pdt, float* __restrict__ pbc,
    float* __restrict__ ysum){
  {
    float4* yz=(float4*)(ysum+(size_t)blockIdx.x*8192);
    #pragma unroll
    for (int i=0;i<8;++i) yz[i*256+threadIdx.x]=make_float4(0.f,0.f,0.f,0.f);
  }
  const int wave=threadIdx.x>>6, lane=threadIdx.x&63;
  const int quad=lane>>4, l16=lane&15;
  const int m0=(wave&1)*80;
  const int n0=blockIdx.x*32+(wave>>1)*16;
  f32x4 acc[5];
  #pragma unroll
  for (int i=0;i<5;++i) acc[i]=(f32x4){0.f,0.f,0.f,0.f};
  for (int k0=0;k0<256;k0+=32){
    bf16x8 a[5], b;
    #pragma unroll
    for (int mi=0;mi<5;++mi)
      a[mi]=cvt_frag(&xpw[(size_t)(m0+mi*16+l16)*256 + k0 + quad*8]);
    b=*(const bf16x8*)&xflatb[(size_t)(n0+l16)*256 + k0 + quad*8];
    #pragma unroll
    for (int mi=0;mi<5;++mi)
      acc[mi]=__builtin_amdgcn_mfma_f32_16x16x32_bf16(a[mi],b,acc[mi],0,0,0);
  }
  #pragma unroll
  for (int mi=0;mi<5;++mi)
    #pragma unroll
    for (int r=0;r<4;++r){
      const int rr=m0+mi*16+quad*4+r;
      const int col=n0+l16;
      const int b_=col>>12, pos=col&4095;
      const int kd=rr/40, c=rr%40, bk=b_*4+kd;
      float v=acc[mi][r];
      if (c<8) pdt[((size_t)bk*4096+pos)*8+c]=v;
      else     pbc[((size_t)bk*4096+pos)*32+(c-8)]=v;
    }
}

// K6a: scan pass A — local scan + local y -> atomic ysum, emit (P,E) bf16.
__global__ __launch_bounds__(256) void k_scanA(const float* __restrict__ pdt,
    const float* __restrict__ pbc, const unsigned short* __restrict__ xflatb,
    const float* __restrict__ dtw, const float* __restrict__ dtb,
    const float* __restrict__ A_logs, const float* __restrict__ Ds,
    unsigned short* __restrict__ Pcb, unsigned short* __restrict__ Heb,
    float* __restrict__ ysum){
  const int bx=blockIdx.x;                 // ((b*4+k)*128+ch)
  const int ch=bx&127, k=(bx>>7)&3, b=bx>>9, bk=b*4+k;
  const int d=threadIdx.x;
  __shared__ float sbc[1024];
  __shared__ float sdt[256];
  for (int i=d;i<1024;i+=256) sbc[i]=pbc[((size_t)bk*4096+(ch<<5))*32+i];
  sdt[d]=pdt[((size_t)bk*4096+(ch<<5))*8+d];
  const float* ap=&A_logs[((k<<8)+d)<<4];
  const float ac0=-__expf(ap[0]);
  bool pw=true;
  #pragma unroll
  for (int n=1;n<16;++n){ float an_=-__expf(ap[n]); pw=pw&&(fabsf(an_-(float)(n+1)*ac0)<=1e-4f*fabsf(an_)); }
  float w8[8];
  {
    float4 w0=*(const float4*)&dtw[(size_t)k*2048+d*8];
    float4 w1=*(const float4*)&dtw[(size_t)k*2048+d*8+4];
    w8[0]=w0.x;w8[1]=w0.y;w8[2]=w0.z;w8[3]=w0.w;w8[4]=w1.x;w8[5]=w1.y;w8[6]=w1.z;w8[7]=w1.w;
  }
  const float dtbd=dtb[(k<<8)+d];
  const float dsv=Ds[(k<<8)+d];
  __syncthreads();
  float h[16]; float sdv=0.f;
  #pragma unroll
  for (int n=0;n<16;++n) h[n]=0.f;
  const unsigned short* up=xflatb+((size_t)b<<12)*256+d;
  if (pw){
    for (int s=0;s<32;++s){
      const int l=(ch<<5)+s;
      float t=dtbd;
      #pragma unroll
      for (int r=0;r<8;++r) t=fmaf(sdt[s*8+r],w8[r],t);
      const float dv=sp_(t);
      const int pos=pos_dir(k,l);
      const float u=bf2f(up[(size_t)pos*256]);
      const float dvu=dv*u;
      sdv+=dv;
      const float q=__expf(dv*ac0);
      float an=q, yl=0.f;
      #pragma unroll
      for (int n4=0;n4<4;++n4){
        float4 bb=*(const float4*)&sbc[s*32+n4*4];
        float4 cc=*(const float4*)&sbc[s*32+16+n4*4];
        h[n4*4+0]=fmaf(h[n4*4+0],an,dvu*bb.x); yl=fmaf(h[n4*4+0],cc.x,yl); an*=q;
        h[n4*4+1]=fmaf(h[n4*4+1],an,dvu*bb.y); yl=fmaf(h[n4*4+1],cc.y,yl); an*=q;
        h[n4*4+2]=fmaf(h[n4*4+2],an,dvu*bb.z); yl=fmaf(h[n4*4+2],cc.z,yl); an*=q;
        h[n4*4+3]=fmaf(h[n4*4+3],an,dvu*bb.w); yl=fmaf(h[n4*4+3],cc.w,yl); an*=q;
      }
      atomicAdd(&ysum[((size_t)((b<<12)+pos))*256+d], yl+u*dsv);
    }
  } else {
    float acoef[16];
    #pragma unroll
    for (int n=0;n<16;++n) acoef[n]=-__expf(ap[n]);
    for (int s=0;s<32;++s){
      const int l=(ch<<5)+s;
      float t=dtbd;
      #pragma unroll
      for (int r=0;r<8;++r) t=fmaf(sdt[s*8+r],w8[r],t);
      const float dv=sp_(t);
      const int pos=pos_dir(k,l);
      const float u=bf2f(up[(size_t)pos*256]);
      const float dvu=dv*u;
      sdv+=dv;
      float yl=0.f;
      #pragma unroll
      for (int n=0;n<16;++n){
        float a=__expf(dv*acoef[n]);
        h[n]=fmaf(h[n],a,dvu*sbc[s*32+n]);
        yl=fmaf(h[n],sbc[s*32+16+n],yl);
      }
      atomicAdd(&ysum[((size_t)((b<<12)+pos))*256+d], yl+u*dsv);
    }
  }
  const size_t obase=(size_t)ch*32768 + ((size_t)bk*256+d)*16;
  if (pw){
    const float qe=__expf(ac0*sdv);
    float an=qe;
    #pragma unroll
    for (int n4=0;n4<4;++n4){
      ushort4 o;
      o.x=f2bf(an); an*=qe; o.y=f2bf(an); an*=qe;
      o.z=f2bf(an); an*=qe; o.w=f2bf(an); an*=qe;
      *(ushort4*)&Pcb[obase+n4*4]=o;
    }
  } else {
    #pragma unroll
    for (int n=0;n<16;++n) Pcb[obase+n]=f2bf(__expf(-__expf(ap[n])*sdv));
  }
  #pragma unroll
  for (int n4=0;n4<4;++n4){
    ushort4 o;
    o.x=f2bf(h[n4*4]); o.y=f2bf(h[n4*4+1]); o.z=f2bf(h[n4*4+2]); o.w=f2bf(h[n4*4+3]);
    *(ushort4*)&Heb[obase+n4*4]=o;
  }
}

// K6b: parallel affine carry-scan over 128 chunks (bf16 state). Hin aliases Pc.
__global__ __launch_bounds__(256) void k_scanB(const unsigned short* Pcb,
    const unsigned short* Heb, unsigned short* Hinb){
  const int g2=threadIdx.x&63, tc=threadIdx.x>>6;
  const int gid=blockIdx.x*64+g2;
  float p[32], e[32];
  #pragma unroll
  for (int i=0;i<32;++i){
    size_t idx=(size_t)(tc*32+i)*32768+gid;
    p[i]=bf2f(Pcb[idx]); e[i]=bf2f(Heb[idx]);
  }
  float P=1.f, E=0.f;
  #pragma unroll
  for (int i=0;i<32;++i){ E=fmaf(E,p[i],e[i]); P*=p[i]; }
  __shared__ float sP[4][64], sE[4][64];
  sP[tc][g2]=P; sE[tc][g2]=E;
  __syncthreads();
  float Hp=0.f;
  for (int t=0;t<tc;++t) Hp=fmaf(Hp,sP[t][g2],sE[t][g2]);
  #pragma unroll
  for (int i=0;i<32;++i){
    Hinb[(size_t)(tc*32+i)*32768+gid]=f2bf(Hp);
    Hp=fmaf(Hp,p[i],e[i]);
  }
}

// K6c: carry correction: ysum[pos,d] += sum_n Hin_n * exp(acoef_n*cumd_s) * C_sn
__global__ __launch_bounds__(256) void k_scanC2(const float* __restrict__ pdt,
    const float* __restrict__ pbc, const float* __restrict__ dtw,
    const float* __restrict__ dtb, const float* __restrict__ A_logs,
    const unsigned short* __restrict__ Hinb, float* __restrict__ ysum){
  const int bx=blockIdx.x;
  const int ch=bx&127, k=(bx>>7)&3, b=bx>>9, bk=b*4+k;
  if (ch==0) return;
  const int d=threadIdx.x;
  __shared__ float sC[512];
  __shared__ float sdt[256];
  for (int i=d;i<512;i+=256){ int s=i>>4,n=i&15; sC[i]=pbc[((size_t)bk*4096+(ch<<5)+s)*32+16+n]; }
  sdt[d]=pdt[((size_t)bk*4096+(ch<<5))*8+d];
  const float* ap=&A_logs[((k<<8)+d)<<4];
  const float ac0=-__expf(ap[0]);
  bool pw=true;
  #pragma unroll
  for (int n=1;n<16;++n){ float an_=-__expf(ap[n]); pw=pw&&(fabsf(an_-(float)(n+1)*ac0)<=1e-4f*fabsf(an_)); }
  float w8[8];
  {
    float4 w0=*(const float4*)&dtw[(size_t)k*2048+d*8];
    float4 w1=*(const float4*)&dtw[(size_t)k*2048+d*8+4];
    w8[0]=w0.x;w8[1]=w0.y;w8[2]=w0.z;w8[3]=w0.w;w8[4]=w1.x;w8[5]=w1.y;w8[6]=w1.z;w8[7]=w1.w;
  }
  const float dtbd=dtb[(k<<8)+d];
  __syncthreads();
  const size_t ibase=(size_t)ch*32768 + ((size_t)bk*256+d)*16;
  float h[16];
  #pragma unroll
  for (int n=0;n<16;++n) h[n]=bf2f(Hinb[ibase+n]);
  if (pw){
    float cumd=0.f;
    for (int s=0;s<32;++s){
      float t=dtbd;
      #pragma unroll
      for (int r=0;r<8;++r) t=fmaf(sdt[s*8+r],w8[r],t);
      cumd+=sp_(t);
      const float q=__expf(ac0*cumd);
      float an=q, corr=0.f;
      #pragma unroll
      for (int n4=0;n4<4;++n4){
        float4 cc=*(const float4*)&sC[s*16+n4*4];
        corr=fmaf(h[n4*4+0]*an,cc.x,corr); an*=q;
        corr=fmaf(h[n4*4+1]*an,cc.y,corr); an*=q;
        corr=fmaf(h[n4*4+2]*an,cc.z,corr); an*=q;
        corr=fmaf(h[n4*4+3]*an,cc.w,corr); an*=q;
      }
      const int l=(ch<<5)+s;
      atomicAdd(&ysum[((size_t)((b<<12)+pos_dir(k,l)))*256+d], corr);
    }
  } else {
    float acoef[16];
    #pragma unroll
    for (int n=0;n<16;++n) acoef[n]=-__expf(ap[n]);
    float cumd=0.f;
    for (int s=0;s<32;++s){
      float t=dtbd;
      #pragma unroll
      for (int r=0;r<8;++r) t=fmaf(sdt[s*8+r],w8[r],t);
      cumd+=sp_(t);
      float corr=0.f;
      #pragma unroll
      for (int n=0;n<16;++n) corr=fmaf(h[n]*__expf(acoef[n]*cumd),sC[s*16+n],corr);
      const int l=(ch<<5)+s;
      atomicAdd(&ysum[((size_t)((b<<12)+pos_dir(k,l)))*256+d], corr);
    }
  }
}

// K10: LayerNorm(256) of ysum, gate with silu(z) -> yg bf16 (B,L,256)
__global__ __launch_bounds__(256) void k_outnorm(const float* __restrict__ ysum,
    const float* __restrict__ g, const float* __restrict__ be,
    const float* __restrict__ z, unsigned short* __restrict__ ygb){
  const int bp=blockIdx.x, d=threadIdx.x;
  float v=ysum[(size_t)bp*256+d];
  float s=v, s2=v*v;
  #pragma unroll
  for (int m=1;m<64;m<<=1){ s+=__shfl_xor(s,m); s2+=__shfl_xor(s2,m); }
  __shared__ float rs[4], rs2[4];
  if ((d&63)==0){ rs[d>>6]=s; rs2[d>>6]=s2; }
  __syncthreads();
  float S=rs[0]+rs[1]+rs[2]+rs[3], S2=rs2[0]+rs2[1]+rs2[2]+rs2[3];
  float mu=S*(1.f/256.f), var=S2*(1.f/256.f)-mu*mu, rstd=rsqrtf(var+1e-5f);
  float ln=(v-mu)*rstd*g[d]+be[d];
  float zv=z[(size_t)bp*256+d];
  ygb[(size_t)bp*256+d]=f2bf(ln*silu_(zv));
}

// K11: outproj MFMA. 256 blocks x 32 cols. mamba = W.yg^T + x1, f32 (B,C,L).
__global__ __launch_bounds__(256) void k_outproj(const unsigned short* __restrict__ ygb,
    const float* __restrict__ W, const float* __restrict__ x1, float* __restrict__ mamba){
  const int wave=threadIdx.x>>6, lane=threadIdx.x&63;
  const int quad=lane>>4, l16=lane&15;
  const int m0=(wave&1)*64;
  const int n0=blockIdx.x*32+(wave>>1)*16;
  f32x4 acc[4];
  #pragma unroll
  for (int i=0;i<4;++i) acc[i]=(f32x4){0.f,0.f,0.f,0.f};
  for (int k0=0;k0<256;k0+=32){
    bf16x8 a[4], b;
    #pragma unroll
    for (int mi=0;mi<4;++mi)
      a[mi]=cvt_frag(&W[(size_t)(m0+mi*16+l16)*256 + k0 + quad*8]);
    b=*(const bf16x8*)&ygb[(size_t)(n0+l16)*256 + k0 + quad*8];
    #pragma unroll
    for (int mi=0;mi<4;++mi)
      acc[mi]=__builtin_amdgcn_mfma_f32_16x16x32_bf16(a[mi],b,acc[mi],0,0,0);
  }
  #pragma unroll
  for (int mi=0;mi<4;++mi)
    #pragma unroll
    for (int r=0;r<4;++r){
      const int c=m0+mi*16+quad*4+r;
      const int col=n0+l16;
      const int b_=col>>12, pos=col&4095;
      const size_t addr=((size_t)((b_<<7)+c))*4096+pos;
      mamba[addr]=acc[mi][r]+x1[addr];
    }
}

// K12: per (b,c): sum / sumsq / max over HW (block reduce, no atomics)
__global__ __launch_bounds__(256) void k_stats(const float* __restrict__ mamba, float* __restrict__ stats){
  const int bc=blockIdx.x, tid=threadIdx.x;
  const float* row=mamba+(size_t)bc*4096;
  float s=0.f,s2=0.f,mx=-3.402823466e38f;
  for (int i=tid;i<4096;i+=256){ float v=row[i]; s+=v; s2=fmaf(v,v,s2); mx=fmaxf(mx,v); }
  #pragma unroll
  for (int m=1;m<64;m<<=1){
    s+=__shfl_xor(s,m); s2+=__shfl_xor(s2,m); mx=fmaxf(mx,__shfl_xor(mx,m));
  }
  __shared__ float r0[4],r1[4],r2[4];
  if ((tid&63)==0){ int wv=tid>>6; r0[wv]=s; r1[wv]=s2; r2[wv]=mx; }
  __syncthreads();
  if (tid==0){
    stats[bc*3+0]=r0[0]+r0[1]+r0[2]+r0[3];
    stats[bc*3+1]=r1[0]+r1[1]+r1[2]+r1[3];
    stats[bc*3+2]=fmaxf(fmaxf(r2[0],r2[1]),fmaxf(r2[2],r2[3]));
  }
}

// K14: fused att + final. Each block (fixed b,c) recomputes the channel-attn
// MLP (~3K MAC) + its group's mu/rstd from stats, then the elementwise tail.
__global__ __launch_bounds__(256) void k_final(const float* __restrict__ mamba,
    const float* __restrict__ x1, const float* __restrict__ stats,
    const float* __restrict__ fc1, const float* __restrict__ fc2,
    const float* __restrict__ gg, const float* __restrict__ gb,
    float* __restrict__ out){
  const int idx=blockIdx.x*256+threadIdx.x;
  const int tid=threadIdx.x;
  const int c=(idx>>12)&127, b=idx>>19;       // block-uniform
  __shared__ float hsum[8];
  __shared__ float smu, srstd, satt;
  if (tid<8){
    float ha=0.f,hm=0.f;
    for (int cc=0;cc<128;++cc){
      float w=fc1[tid*128+cc];
      const float* st=&stats[((b<<7)+cc)*3];
      ha=fmaf(w,st[0]*(1.f/4096.f),ha);
      hm=fmaf(w,st[2],hm);
    }
    hsum[tid]=fmaxf(ha,0.f)+fmaxf(hm,0.f);
  }
  __syncthreads();
  if (tid<64){
    const int cg=((c>>6)<<6)+tid;             // channel within this group
    float a=0.f;
    #pragma unroll
    for (int i=0;i<8;++i) a=fmaf(fc2[cg*8+i],hsum[i],a);
    a=sigm_(a);
    const float* st=&stats[((b<<7)+cg)*3];
    float sum1=a*st[0];
    float sum2=a*a*st[1];
    #pragma unroll
    for (int m=1;m<64;m<<=1){ sum1+=__shfl_xor(sum1,m); sum2+=__shfl_xor(sum2,m); }
    if (tid==0){
      const float inv=1.f/(64.f*4096.f);
      float mu=sum1*inv, ex2=sum2*inv;
      smu=mu; srstd=rsqrtf(ex2-mu*mu+1e-5f);
      float ao=0.f;
      #pragma unroll
      for (int i=0;i<8;++i) ao=fmaf(fc2[c*8+i],hsum[i],ao);
      satt=sigm_(ao);
    }
  }
  __syncthreads();
  float v=mamba[idx]*satt;
  float vn=(v-smu)*srstd*gg[c]+gb[c];
  out[idx]=silu_(vn)+x1[idx];
}

extern "C" void kernel_launch(void* const* d_in, const int* in_sizes, int n_in,
                              void* d_out, int out_size, void* d_ws, size_t ws_size,
                              hipStream_t stream){
  (void)in_sizes; (void)n_in; (void)out_size; (void)ws_size;
  const float* x        =(const float*)d_in[0];
  const float* convin_w =(const float*)d_in[1];
  const float* convin_b =(const float*)d_in[2];
  const float* ln_g     =(const float*)d_in[3];
  const float* ln_b     =(const float*)d_in[4];
  const float* in_proj_w=(const float*)d_in[5];
  const float* conv_w   =(const float*)d_in[6];
  const float* conv_b   =(const float*)d_in[7];
  const float* x_proj_w =(const float*)d_in[8];
  const float* dt_w     =(const float*)d_in[9];
  const float* dt_b     =(const float*)d_in[10];
  const float* A_logs   =(const float*)d_in[11];
  const float* Ds       =(const float*)d_in[12];
  const float* outnorm_g=(const float*)d_in[13];
  const float* outnorm_b=(const float*)d_in[14];
  const float* out_proj_w=(const float*)d_in[15];
  const float* ca_fc1_w =(const float*)d_in[16];
  const float* ca_fc2_w =(const float*)d_in[17];
  const float* gn_g     =(const float*)d_in[18];
  const float* gn_b     =(const float*)d_in[19];

  float* ws=(float*)d_ws;
  float*          x1     =ws+0;          // [0,1M)      x1ln .. final
  float*          z      =ws+1048576;    // [1M,3M)     inproj .. outnorm
  unsigned short* xmpreb =(unsigned short*)(ws+3145728); // [3M,4M) bf16 2M; inproj .. dwconv
  unsigned short* mlnb   =(unsigned short*)(ws+5242880); // [5M,6M) bf16 2M; x1ln .. inproj
  unsigned short* xflatb =(unsigned short*)(ws+6291456); // [6M,7M) bf16 2M; dwconv .. scanA
  float*          pdt    =ws+8388608;    // [8M,+256K)  proj .. scanC2
  float*          pbc    =ws+8912896;    // [8.5M,9.5M) proj .. scanC2
  unsigned short* Pcb    =(unsigned short*)(ws+10485760); // [10M,12M) bf16 4.2M == Hin
  unsigned short* Heb    =(unsigned short*)(ws+12582912); // [12M,14M) bf16 4.2M
  float*          ysum   =ws+18874368;   // [18M,20M)   zeroed in k_proj .. outnorm
  unsigned short* ygb    =(unsigned short*)(ws+3145728); // aliases xmpreb (dead after dwconv)
  float*          mamba  =ws+5242880;    // aliases mlnb (dead after inproj)
  float*          stats  =ws+27262976;

  const dim3 blk(256);
  k_x1ln   <<<dim3(64,2),   blk,0,stream>>>(x, convin_w, convin_b, ln_g, ln_b, x1, mlnb);
  k_inproj <<<dim3(8,64),   blk,0,stream>>>(mlnb, in_proj_w, xmpreb, z);
  k_dwconv <<<dim3(512),    blk,0,stream>>>(xmpreb, conv_w, conv_b, xflatb);
  k_proj   <<<dim3(256),    blk,0,stream>>>(xflatb, x_proj_w, pdt, pbc, ysum);
  k_scanA  <<<dim3(1024),   blk,0,stream>>>(pdt, pbc, xflatb, dt_w, dt_b, A_logs, Ds, Pcb, Heb, ysum);
  k_scanB  <<<dim3(512),    blk,0,stream>>>(Pcb, Heb, Pcb /*Hin*/);
  k_scanC2 <<<dim3(1024),   blk,0,stream>>>(pdt, pbc, dt_w, dt_b, A_logs, Pcb /*Hin*/, ysum);
  k_outnorm<<<dim3(8192),   blk,0,stream>>>(ysum, outnorm_g, outnorm_b, z, ygb);
  k_outproj<<<dim3(256),    blk,0,stream>>>(ygb, out_proj_w, x1, mamba);
  k_stats  <<<dim3(256),    blk,0,stream>>>(mamba, stats);
  k_final  <<<dim3(4096),   blk,0,stream>>>(mamba, x1, stats, ca_fc1_w, ca_fc2_w, gn_g, gn_b, (float*)d_out);
}

// Round 12
// 252.986 us; speedup vs baseline: 1.0578x; 1.0578x over previous
//
#include <hip/hip_runtime.h>
#include <math.h>

// ---------------------------------------------------------------------------
// MambaCaMix on MI355X — round 12: byte-exact revert to R8 (best measured,
// 254.6us). R10/R11 showed att->final fusion and ysum-zero-in-proj are net
// negative (serial per-block prologue / write burst in latency-bound GEMM).
// Session lessons: (1) no parallel-work fusion into low-occupancy MFMA
// kernels; (2) no high-frequency same-line cross-XCD atomics; (3) coop launch
// silently fails under this harness; (4) dispatch-removal tricks below the
// ~5us noise floor are not worth in-kernel cost.
// B=2, Cin=64, C=128, H=W=64 (L=4096), D_INNER=256, N_STATE=16, DT_RANK=8, K=4
// ---------------------------------------------------------------------------

#define DEV __device__ __forceinline__

typedef __attribute__((ext_vector_type(8))) short bf16x8;
typedef __attribute__((ext_vector_type(4))) float f32x4;

DEV float sigm_(float x){ return 1.f/(1.f+__expf(-x)); }
DEV float silu_(float x){ return x*sigm_(x); }
DEV float sp_(float x){ return (x>15.f)? x : __logf(1.f+__expf(x)); }

DEV unsigned short f2bf(float f){
  union{float f; unsigned u;} v; v.f=f;
  unsigned r=v.u + 0x7FFFu + ((v.u>>16)&1u);
  return (unsigned short)(r>>16);
}
DEV float bf2f(unsigned short h){ union{unsigned u; float f;} v; v.u=((unsigned)h)<<16; return v.f; }

DEV int pos_dir(int k, int l){
  switch(k&3){
    case 0: return l;
    case 1: return ((l&63)<<6)|(l>>6);
    case 2: return 4095-l;
    default:{ int m=4095-l; return ((m&63)<<6)|(m>>6); }
  }
}

DEV bf16x8 cvt_frag(const float* p){
  float4 q0=*(const float4*)p, q1=*(const float4*)(p+4);
  bf16x8 t;
  t[0]=(short)f2bf(q0.x); t[1]=(short)f2bf(q0.y); t[2]=(short)f2bf(q0.z); t[3]=(short)f2bf(q0.w);
  t[4]=(short)f2bf(q1.x); t[5]=(short)f2bf(q1.y); t[6]=(short)f2bf(q1.z); t[7]=(short)f2bf(q1.w);
  return t;
}

// K1: fused 1x1 conv-in + LayerNorm(128). Writes x1 (B,C,L) f32, mln bf16 (B*L,128).
__global__ __launch_bounds__(256) void k_x1ln(const float* __restrict__ x,
    const float* __restrict__ W, const float* __restrict__ bias,
    const float* __restrict__ g, const float* __restrict__ be,
    float* __restrict__ x1, unsigned short* __restrict__ mlnb){
  const int b=blockIdx.y, p0=blockIdx.x*64;
  __shared__ float sw[64*132];
  __shared__ float sx[64*68];
  __shared__ float red[2][16][68];
  __shared__ float smu[64], srs[64];
  const int tid=threadIdx.x, tx=tid&15, ty=tid>>4;
  for (int i=tid;i<8192;i+=256){ int c=i&63,o=i>>6; sw[c*132+o]=W[o*64+c]; }
  for (int i=tid;i<4096;i+=256){ int c=i>>6,p=i&63; sx[c*68+p]=x[((size_t)(b*64+c))*4096+p0+p]; }
  __syncthreads();
  float acc[8][4]={};
  for (int c=0;c<64;++c){
    float4 a0=*(const float4*)&sw[c*132+ty*8];
    float4 a1=*(const float4*)&sw[c*132+ty*8+4];
    float4 bv=*(const float4*)&sx[c*68+tx*4];
    acc[0][0]=fmaf(a0.x,bv.x,acc[0][0]); acc[0][1]=fmaf(a0.x,bv.y,acc[0][1]); acc[0][2]=fmaf(a0.x,bv.z,acc[0][2]); acc[0][3]=fmaf(a0.x,bv.w,acc[0][3]);
    acc[1][0]=fmaf(a0.y,bv.x,acc[1][0]); acc[1][1]=fmaf(a0.y,bv.y,acc[1][1]); acc[1][2]=fmaf(a0.y,bv.z,acc[1][2]); acc[1][3]=fmaf(a0.y,bv.w,acc[1][3]);
    acc[2][0]=fmaf(a0.z,bv.x,acc[2][0]); acc[2][1]=fmaf(a0.z,bv.y,acc[2][1]); acc[2][2]=fmaf(a0.z,bv.z,acc[2][2]); acc[2][3]=fmaf(a0.z,bv.w,acc[2][3]);
    acc[3][0]=fmaf(a0.w,bv.x,acc[3][0]); acc[3][1]=fmaf(a0.w,bv.y,acc[3][1]); acc[3][2]=fmaf(a0.w,bv.z,acc[3][2]); acc[3][3]=fmaf(a0.w,bv.w,acc[3][3]);
    acc[4][0]=fmaf(a1.x,bv.x,acc[4][0]); acc[4][1]=fmaf(a1.x,bv.y,acc[4][1]); acc[4][2]=fmaf(a1.x,bv.z,acc[4][2]); acc[4][3]=fmaf(a1.x,bv.w,acc[4][3]);
    acc[5][0]=fmaf(a1.y,bv.x,acc[5][0]); acc[5][1]=fmaf(a1.y,bv.y,acc[5][1]); acc[5][2]=fmaf(a1.y,bv.z,acc[5][2]); acc[5][3]=fmaf(a1.y,bv.w,acc[5][3]);
    acc[6][0]=fmaf(a1.z,bv.x,acc[6][0]); acc[6][1]=fmaf(a1.z,bv.y,acc[6][1]); acc[6][2]=fmaf(a1.z,bv.z,acc[6][2]); acc[6][3]=fmaf(a1.z,bv.w,acc[6][3]);
    acc[7][0]=fmaf(a1.w,bv.x,acc[7][0]); acc[7][1]=fmaf(a1.w,bv.y,acc[7][1]); acc[7][2]=fmaf(a1.w,bv.z,acc[7][2]); acc[7][3]=fmaf(a1.w,bv.w,acc[7][3]);
  }
  float xr[8][4];
  #pragma unroll
  for (int i=0;i<8;++i){
    float bs=bias[ty*8+i];
    #pragma unroll
    for (int j=0;j<4;++j) xr[i][j]=acc[i][j]+bs;
  }
  {
    float s[4]={},s2[4]={};
    #pragma unroll
    for (int i=0;i<8;++i)
      #pragma unroll
      for (int j=0;j<4;++j){ s[j]+=xr[i][j]; s2[j]=fmaf(xr[i][j],xr[i][j],s2[j]); }
    #pragma unroll
    for (int j=0;j<4;++j){ red[0][ty][tx*4+j]=s[j]; red[1][ty][tx*4+j]=s2[j]; }
  }
  __syncthreads();
  if (tid<64){
    float S=0.f,S2=0.f;
    #pragma unroll
    for (int t=0;t<16;++t){ S+=red[0][t][tid]; S2+=red[1][t][tid]; }
    float mu=S*(1.f/128.f), var=S2*(1.f/128.f)-mu*mu;
    smu[tid]=mu; srs[tid]=rsqrtf(var+1e-5f);
  }
  __syncthreads();
  float* lnt=sw;
  #pragma unroll
  for (int i=0;i<8;++i){
    int o=ty*8+i;
    float gv=g[o], bev=be[o];
    #pragma unroll
    for (int j=0;j<4;++j){
      int p=tx*4+j;
      lnt[o*66+p]=(xr[i][j]-smu[p])*srs[p]*gv+bev;
    }
    *(float4*)&x1[((size_t)(b*128+o))*4096+p0+tx*4]=make_float4(xr[i][0],xr[i][1],xr[i][2],xr[i][3]);
  }
  __syncthreads();
  for (int i=tid;i<8192;i+=256){ int p=i>>7,o=i&127; mlnb[((size_t)(b*4096+p0+p))*128+o]=f2bf(lnt[o*66+p]); }
}

// K3: inproj MFMA. M=8192, N=512, K=128. cols<256 -> xmpre bf16; cols>=256 -> z f32.
__global__ __launch_bounds__(256) void k_inproj(const unsigned short* __restrict__ mlnb,
    const float* __restrict__ W, unsigned short* __restrict__ xmpreb, float* __restrict__ z){
  const int wave=threadIdx.x>>6, lane=threadIdx.x&63;
  const int quad=lane>>4, l16=lane&15;
  const int m0=blockIdx.y*128+(wave>>1)*64;
  const int n0=blockIdx.x*64+(wave&1)*32;
  f32x4 acc[4][2];
  #pragma unroll
  for (int i=0;i<4;++i)
    #pragma unroll
    for (int j=0;j<2;++j) acc[i][j]=(f32x4){0.f,0.f,0.f,0.f};
  for (int k0=0;k0<128;k0+=32){
    bf16x8 a[4], b[2];
    #pragma unroll
    for (int mi=0;mi<4;++mi)
      a[mi]=*(const bf16x8*)&mlnb[(size_t)(m0+mi*16+l16)*128 + k0 + quad*8];
    #pragma unroll
    for (int ni=0;ni<2;++ni)
      b[ni]=cvt_frag(&W[(size_t)(n0+ni*16+l16)*128 + k0 + quad*8]);
    #pragma unroll
    for (int mi=0;mi<4;++mi)
      #pragma unroll
      for (int ni=0;ni<2;++ni)
        acc[mi][ni]=__builtin_amdgcn_mfma_f32_16x16x32_bf16(a[mi],b[ni],acc[mi][ni],0,0,0);
  }
  #pragma unroll
  for (int mi=0;mi<4;++mi)
    #pragma unroll
    for (int ni=0;ni<2;++ni)
      #pragma unroll
      for (int r=0;r<4;++r){
        const int row=m0+mi*16+quad*4+r;
        const int col=n0+ni*16+l16;
        float v=acc[mi][ni][r];
        if (col<256) xmpreb[(size_t)row*256+col]=f2bf(v);
        else         z[(size_t)row*256+(col-256)]=v;
      }
}

// K4: depthwise 3x3 conv + bias + SiLU, bf16 in -> bf16 out (B,L,256)
__global__ __launch_bounds__(256) void k_dwconv(const unsigned short* __restrict__ xmpreb,
    const float* __restrict__ cw, const float* __restrict__ cb, unsigned short* __restrict__ xflatb){
  __shared__ float sw[2304];
  __shared__ float sb[256];
  const int tid=threadIdx.x;
  for (int i=tid;i<2304;i+=256) sw[i]=cw[i];
  sb[tid]=cb[tid];
  __syncthreads();
  const int bp0=blockIdx.x*16;
  const int b=bp0>>12, p0=bp0&4095;
  const int dq=tid&63, pg=tid>>6;
  const int d0=dq*4;
  float wr[9][4];
  #pragma unroll
  for (int t=0;t<9;++t)
    #pragma unroll
    for (int c=0;c<4;++c) wr[t][c]=sw[(d0+c)*9+t];
  const float4 bias=make_float4(sb[d0],sb[d0+1],sb[d0+2],sb[d0+3]);
  #pragma unroll
  for (int j=0;j<4;++j){
    const int p=p0+pg*4+j;
    const int h=p>>6, w=p&63;
    float4 acc=bias;
    #pragma unroll
    for (int dh=-1;dh<=1;++dh){
      int hh=h+dh; if ((unsigned)hh>=64u) continue;
      #pragma unroll
      for (int dw=-1;dw<=1;++dw){
        int ww=w+dw; if ((unsigned)ww>=64u) continue;
        const int t=(dh+1)*3+(dw+1);
        ushort4 u4=*(const ushort4*)&xmpreb[((size_t)((b<<12)+hh*64+ww))*256+d0];
        acc.x=fmaf(bf2f(u4.x),wr[t][0],acc.x); acc.y=fmaf(bf2f(u4.y),wr[t][1],acc.y);
        acc.z=fmaf(bf2f(u4.z),wr[t][2],acc.z); acc.w=fmaf(bf2f(u4.w),wr[t][3],acc.w);
      }
    }
    ushort4 o;
    o.x=f2bf(silu_(acc.x)); o.y=f2bf(silu_(acc.y)); o.z=f2bf(silu_(acc.z)); o.w=f2bf(silu_(acc.w));
    *(ushort4*)&xflatb[((size_t)((b<<12)+p))*256+d0]=o;
  }
}

// K5: proj MFMA. M=160 (r), N=8192, K=256. 256 blocks x 32 cols.
__global__ __launch_bounds__(256) void k_proj(const unsigned short* __restrict__ xflatb,
    const float* __restrict__ xpw, float* __restrict__ pdt, float* __restrict__ pbc){
  const int wave=threadIdx.x>>6, lane=threadIdx.x&63;
  const int quad=lane>>4, l16=lane&15;
  const int m0=(wave&1)*80;
  const int n0=blockIdx.x*32+(wave>>1)*16;
  f32x4 acc[5];
  #pragma unroll
  for (int i=0;i<5;++i) acc[i]=(f32x4){0.f,0.f,0.f,0.f};
  for (int k0=0;k0<256;k0+=32){
    bf16x8 a[5], b;
    #pragma unroll
    for (int mi=0;mi<5;++mi)
      a[mi]=cvt_frag(&xpw[(size_t)(m0+mi*16+l16)*256 + k0 + quad*8]);
    b=*(const bf16x8*)&xflatb[(size_t)(n0+l16)*256 + k0 + quad*8];
    #pragma unroll
    for (int mi=0;mi<5;++mi)
      acc[mi]=__builtin_amdgcn_mfma_f32_16x16x32_bf16(a[mi],b,acc[mi],0,0,0);
  }
  #pragma unroll
  for (int mi=0;mi<5;++mi)
    #pragma unroll
    for (int r=0;r<4;++r){
      const int rr=m0+mi*16+quad*4+r;
      const int col=n0+l16;
      const int b_=col>>12, pos=col&4095;
      const int kd=rr/40, c=rr%40, bk=b_*4+kd;
      float v=acc[mi][r];
      if (c<8) pdt[((size_t)bk*4096+pos)*8+c]=v;
      else     pbc[((size_t)bk*4096+pos)*32+(c-8)]=v;
    }
}

// K6a: scan pass A — local scan + local y -> atomic ysum, emit (P,E) bf16.
__global__ __launch_bounds__(256) void k_scanA(const float* __restrict__ pdt,
    const float* __restrict__ pbc, const unsigned short* __restrict__ xflatb,
    const float* __restrict__ dtw, const float* __restrict__ dtb,
    const float* __restrict__ A_logs, const float* __restrict__ Ds,
    unsigned short* __restrict__ Pcb, unsigned short* __restrict__ Heb,
    float* __restrict__ ysum){
  const int bx=blockIdx.x;                 // ((b*4+k)*128+ch)
  const int ch=bx&127, k=(bx>>7)&3, b=bx>>9, bk=b*4+k;
  const int d=threadIdx.x;
  __shared__ float sbc[1024];
  __shared__ float sdt[256];
  for (int i=d;i<1024;i+=256) sbc[i]=pbc[((size_t)bk*4096+(ch<<5))*32+i];
  sdt[d]=pdt[((size_t)bk*4096+(ch<<5))*8+d];
  const float* ap=&A_logs[((k<<8)+d)<<4];
  const float ac0=-__expf(ap[0]);
  bool pw=true;
  #pragma unroll
  for (int n=1;n<16;++n){ float an_=-__expf(ap[n]); pw=pw&&(fabsf(an_-(float)(n+1)*ac0)<=1e-4f*fabsf(an_)); }
  float w8[8];
  {
    float4 w0=*(const float4*)&dtw[(size_t)k*2048+d*8];
    float4 w1=*(const float4*)&dtw[(size_t)k*2048+d*8+4];
    w8[0]=w0.x;w8[1]=w0.y;w8[2]=w0.z;w8[3]=w0.w;w8[4]=w1.x;w8[5]=w1.y;w8[6]=w1.z;w8[7]=w1.w;
  }
  const float dtbd=dtb[(k<<8)+d];
  const float dsv=Ds[(k<<8)+d];
  __syncthreads();
  float h[16]; float sdv=0.f;
  #pragma unroll
  for (int n=0;n<16;++n) h[n]=0.f;
  const unsigned short* up=xflatb+((size_t)b<<12)*256+d;
  if (pw){
    for (int s=0;s<32;++s){
      const int l=(ch<<5)+s;
      float t=dtbd;
      #pragma unroll
      for (int r=0;r<8;++r) t=fmaf(sdt[s*8+r],w8[r],t);
      const float dv=sp_(t);
      const int pos=pos_dir(k,l);
      const float u=bf2f(up[(size_t)pos*256]);
      const float dvu=dv*u;
      sdv+=dv;
      const float q=__expf(dv*ac0);
      float an=q, yl=0.f;
      #pragma unroll
      for (int n4=0;n4<4;++n4){
        float4 bb=*(const float4*)&sbc[s*32+n4*4];
        float4 cc=*(const float4*)&sbc[s*32+16+n4*4];
        h[n4*4+0]=fmaf(h[n4*4+0],an,dvu*bb.x); yl=fmaf(h[n4*4+0],cc.x,yl); an*=q;
        h[n4*4+1]=fmaf(h[n4*4+1],an,dvu*bb.y); yl=fmaf(h[n4*4+1],cc.y,yl); an*=q;
        h[n4*4+2]=fmaf(h[n4*4+2],an,dvu*bb.z); yl=fmaf(h[n4*4+2],cc.z,yl); an*=q;
        h[n4*4+3]=fmaf(h[n4*4+3],an,dvu*bb.w); yl=fmaf(h[n4*4+3],cc.w,yl); an*=q;
      }
      atomicAdd(&ysum[((size_t)((b<<12)+pos))*256+d], yl+u*dsv);
    }
  } else {
    float acoef[16];
    #pragma unroll
    for (int n=0;n<16;++n) acoef[n]=-__expf(ap[n]);
    for (int s=0;s<32;++s){
      const int l=(ch<<5)+s;
      float t=dtbd;
      #pragma unroll
      for (int r=0;r<8;++r) t=fmaf(sdt[s*8+r],w8[r],t);
      const float dv=sp_(t);
      const int pos=pos_dir(k,l);
      const float u=bf2f(up[(size_t)pos*256]);
      const float dvu=dv*u;
      sdv+=dv;
      float yl=0.f;
      #pragma unroll
      for (int n=0;n<16;++n){
        float a=__expf(dv*acoef[n]);
        h[n]=fmaf(h[n],a,dvu*sbc[s*32+n]);
        yl=fmaf(h[n],sbc[s*32+16+n],yl);
      }
      atomicAdd(&ysum[((size_t)((b<<12)+pos))*256+d], yl+u*dsv);
    }
  }
  const size_t obase=(size_t)ch*32768 + ((size_t)bk*256+d)*16;
  if (pw){
    const float qe=__expf(ac0*sdv);
    float an=qe;
    #pragma unroll
    for (int n4=0;n4<4;++n4){
      ushort4 o;
      o.x=f2bf(an); an*=qe; o.y=f2bf(an); an*=qe;
      o.z=f2bf(an); an*=qe; o.w=f2bf(an); an*=qe;
      *(ushort4*)&Pcb[obase+n4*4]=o;
    }
  } else {
    #pragma unroll
    for (int n=0;n<16;++n) Pcb[obase+n]=f2bf(__expf(-__expf(ap[n])*sdv));
  }
  #pragma unroll
  for (int n4=0;n4<4;++n4){
    ushort4 o;
    o.x=f2bf(h[n4*4]); o.y=f2bf(h[n4*4+1]); o.z=f2bf(h[n4*4+2]); o.w=f2bf(h[n4*4+3]);
    *(ushort4*)&Heb[obase+n4*4]=o;
  }
}

// K6b: parallel affine carry-scan over 128 chunks (bf16 state). Hin aliases Pc.
__global__ __launch_bounds__(256) void k_scanB(const unsigned short* Pcb,
    const unsigned short* Heb, unsigned short* Hinb){
  const int g2=threadIdx.x&63, tc=threadIdx.x>>6;
  const int gid=blockIdx.x*64+g2;
  float p[32], e[32];
  #pragma unroll
  for (int i=0;i<32;++i){
    size_t idx=(size_t)(tc*32+i)*32768+gid;
    p[i]=bf2f(Pcb[idx]); e[i]=bf2f(Heb[idx]);
  }
  float P=1.f, E=0.f;
  #pragma unroll
  for (int i=0;i<32;++i){ E=fmaf(E,p[i],e[i]); P*=p[i]; }
  __shared__ float sP[4][64], sE[4][64];
  sP[tc][g2]=P; sE[tc][g2]=E;
  __syncthreads();
  float Hp=0.f;
  for (int t=0;t<tc;++t) Hp=fmaf(Hp,sP[t][g2],sE[t][g2]);
  #pragma unroll
  for (int i=0;i<32;++i){
    Hinb[(size_t)(tc*32+i)*32768+gid]=f2bf(Hp);
    Hp=fmaf(Hp,p[i],e[i]);
  }
}

// K6c: carry correction: ysum[pos,d] += sum_n Hin_n * exp(acoef_n*cumd_s) * C_sn
__global__ __launch_bounds__(256) void k_scanC2(const float* __restrict__ pdt,
    const float* __restrict__ pbc, const float* __restrict__ dtw,
    const float* __restrict__ dtb, const float* __restrict__ A_logs,
    const unsigned short* __restrict__ Hinb, float* __restrict__ ysum){
  const int bx=blockIdx.x;
  const int ch=bx&127, k=(bx>>7)&3, b=bx>>9, bk=b*4+k;
  if (ch==0) return;
  const int d=threadIdx.x;
  __shared__ float sC[512];
  __shared__ float sdt[256];
  for (int i=d;i<512;i+=256){ int s=i>>4,n=i&15; sC[i]=pbc[((size_t)bk*4096+(ch<<5)+s)*32+16+n]; }
  sdt[d]=pdt[((size_t)bk*4096+(ch<<5))*8+d];
  const float* ap=&A_logs[((k<<8)+d)<<4];
  const float ac0=-__expf(ap[0]);
  bool pw=true;
  #pragma unroll
  for (int n=1;n<16;++n){ float an_=-__expf(ap[n]); pw=pw&&(fabsf(an_-(float)(n+1)*ac0)<=1e-4f*fabsf(an_)); }
  float w8[8];
  {
    float4 w0=*(const float4*)&dtw[(size_t)k*2048+d*8];
    float4 w1=*(const float4*)&dtw[(size_t)k*2048+d*8+4];
    w8[0]=w0.x;w8[1]=w0.y;w8[2]=w0.z;w8[3]=w0.w;w8[4]=w1.x;w8[5]=w1.y;w8[6]=w1.z;w8[7]=w1.w;
  }
  const float dtbd=dtb[(k<<8)+d];
  __syncthreads();
  const size_t ibase=(size_t)ch*32768 + ((size_t)bk*256+d)*16;
  float h[16];
  #pragma unroll
  for (int n=0;n<16;++n) h[n]=bf2f(Hinb[ibase+n]);
  if (pw){
    float cumd=0.f;
    for (int s=0;s<32;++s){
      float t=dtbd;
      #pragma unroll
      for (int r=0;r<8;++r) t=fmaf(sdt[s*8+r],w8[r],t);
      cumd+=sp_(t);
      const float q=__expf(ac0*cumd);
      float an=q, corr=0.f;
      #pragma unroll
      for (int n4=0;n4<4;++n4){
        float4 cc=*(const float4*)&sC[s*16+n4*4];
        corr=fmaf(h[n4*4+0]*an,cc.x,corr); an*=q;
        corr=fmaf(h[n4*4+1]*an,cc.y,corr); an*=q;
        corr=fmaf(h[n4*4+2]*an,cc.z,corr); an*=q;
        corr=fmaf(h[n4*4+3]*an,cc.w,corr); an*=q;
      }
      const int l=(ch<<5)+s;
      atomicAdd(&ysum[((size_t)((b<<12)+pos_dir(k,l)))*256+d], corr);
    }
  } else {
    float acoef[16];
    #pragma unroll
    for (int n=0;n<16;++n) acoef[n]=-__expf(ap[n]);
    float cumd=0.f;
    for (int s=0;s<32;++s){
      float t=dtbd;
      #pragma unroll
      for (int r=0;r<8;++r) t=fmaf(sdt[s*8+r],w8[r],t);
      cumd+=sp_(t);
      float corr=0.f;
      #pragma unroll
      for (int n=0;n<16;++n) corr=fmaf(h[n]*__expf(acoef[n]*cumd),sC[s*16+n],corr);
      const int l=(ch<<5)+s;
      atomicAdd(&ysum[((size_t)((b<<12)+pos_dir(k,l)))*256+d], corr);
    }
  }
}

// K10: LayerNorm(256) of ysum, gate with silu(z) -> yg bf16 (B,L,256)
__global__ __launch_bounds__(256) void k_outnorm(const float* __restrict__ ysum,
    const float* __restrict__ g, const float* __restrict__ be,
    const float* __restrict__ z, unsigned short* __restrict__ ygb){
  const int bp=blockIdx.x, d=threadIdx.x;
  float v=ysum[(size_t)bp*256+d];
  float s=v, s2=v*v;
  #pragma unroll
  for (int m=1;m<64;m<<=1){ s+=__shfl_xor(s,m); s2+=__shfl_xor(s2,m); }
  __shared__ float rs[4], rs2[4];
  if ((d&63)==0){ rs[d>>6]=s; rs2[d>>6]=s2; }
  __syncthreads();
  float S=rs[0]+rs[1]+rs[2]+rs[3], S2=rs2[0]+rs2[1]+rs2[2]+rs2[3];
  float mu=S*(1.f/256.f), var=S2*(1.f/256.f)-mu*mu, rstd=rsqrtf(var+1e-5f);
  float ln=(v-mu)*rstd*g[d]+be[d];
  float zv=z[(size_t)bp*256+d];
  ygb[(size_t)bp*256+d]=f2bf(ln*silu_(zv));
}

// K11: outproj MFMA. 256 blocks x 32 cols. mamba = W.yg^T + x1, f32 (B,C,L).
__global__ __launch_bounds__(256) void k_outproj(const unsigned short* __restrict__ ygb,
    const float* __restrict__ W, const float* __restrict__ x1, float* __restrict__ mamba){
  const int wave=threadIdx.x>>6, lane=threadIdx.x&63;
  const int quad=lane>>4, l16=lane&15;
  const int m0=(wave&1)*64;
  const int n0=blockIdx.x*32+(wave>>1)*16;
  f32x4 acc[4];
  #pragma unroll
  for (int i=0;i<4;++i) acc[i]=(f32x4){0.f,0.f,0.f,0.f};
  for (int k0=0;k0<256;k0+=32){
    bf16x8 a[4], b;
    #pragma unroll
    for (int mi=0;mi<4;++mi)
      a[mi]=cvt_frag(&W[(size_t)(m0+mi*16+l16)*256 + k0 + quad*8]);
    b=*(const bf16x8*)&ygb[(size_t)(n0+l16)*256 + k0 + quad*8];
    #pragma unroll
    for (int mi=0;mi<4;++mi)
      acc[mi]=__builtin_amdgcn_mfma_f32_16x16x32_bf16(a[mi],b,acc[mi],0,0,0);
  }
  #pragma unroll
  for (int mi=0;mi<4;++mi)
    #pragma unroll
    for (int r=0;r<4;++r){
      const int c=m0+mi*16+quad*4+r;
      const int col=n0+l16;
      const int b_=col>>12, pos=col&4095;
      const size_t addr=((size_t)((b_<<7)+c))*4096+pos;
      mamba[addr]=acc[mi][r]+x1[addr];
    }
}

// K12: per (b,c): sum / sumsq / max over HW (block reduce, no atomics)
__global__ __launch_bounds__(256) void k_stats(const float* __restrict__ mamba, float* __restrict__ stats){
  const int bc=blockIdx.x, tid=threadIdx.x;
  const float* row=mamba+(size_t)bc*4096;
  float s=0.f,s2=0.f,mx=-3.402823466e38f;
  for (int i=tid;i<4096;i+=256){ float v=row[i]; s+=v; s2=fmaf(v,v,s2); mx=fmaxf(mx,v); }
  #pragma unroll
  for (int m=1;m<64;m<<=1){
    s+=__shfl_xor(s,m); s2+=__shfl_xor(s2,m); mx=fmaxf(mx,__shfl_xor(mx,m));
  }
  __shared__ float r0[4],r1[4],r2[4];
  if ((tid&63)==0){ int wv=tid>>6; r0[wv]=s; r1[wv]=s2; r2[wv]=mx; }
  __syncthreads();
  if (tid==0){
    stats[bc*3+0]=r0[0]+r0[1]+r0[2]+r0[3];
    stats[bc*3+1]=r1[0]+r1[1]+r1[2]+r1[3];
    stats[bc*3+2]=fmaxf(fmaxf(r2[0],r2[1]),fmaxf(r2[2],r2[3]));
  }
}

// K13: channel-attention MLP + group-norm stats
__global__ __launch_bounds__(256) void k_att(const float* __restrict__ stats,
    const float* __restrict__ fc1, const float* __restrict__ fc2,
    float* __restrict__ att, float* __restrict__ gstat){
  __shared__ float avg[2][128], mxs[2][128], S1[2][128], S2[2][128], hsum[2][8], attv[2][128];
  const int tid=threadIdx.x, b=tid>>7, c=tid&127;
  float s1=stats[tid*3], s2=stats[tid*3+1], m=stats[tid*3+2];
  avg[b][c]=s1*(1.f/4096.f); mxs[b][c]=m; S1[b][c]=s1; S2[b][c]=s2;
  __syncthreads();
  if (tid<16){
    int bb=tid>>3, i=tid&7;
    float ha=0.f,hm=0.f;
    for (int cc=0;cc<128;++cc){ float w=fc1[i*128+cc]; ha=fmaf(w,avg[bb][cc],ha); hm=fmaf(w,mxs[bb][cc],hm); }
    hsum[bb][i]=fmaxf(ha,0.f)+fmaxf(hm,0.f);
  }
  __syncthreads();
  float sacc=0.f;
  #pragma unroll
  for (int i=0;i<8;++i) sacc=fmaf(fc2[c*8+i],hsum[b][i],sacc);
  float a=sigm_(sacc);
  attv[b][c]=a; att[tid]=a;
  __syncthreads();
  if (tid<4){
    int bb=tid>>1, gp=tid&1;
    float sum1=0.f,sum2=0.f;
    for (int cc=0;cc<64;++cc){
      int c2=gp*64+cc; float av=attv[bb][c2];
      sum1=fmaf(av,S1[bb][c2],sum1);
      sum2=fmaf(av*av,S2[bb][c2],sum2);
    }
    const float inv=1.f/(64.f*4096.f);
    float mu=sum1*inv, ex2=sum2*inv, var=ex2-mu*mu;
    gstat[tid*2]=mu; gstat[tid*2+1]=rsqrtf(var+1e-5f);
  }
}

// K14: out = silu(groupnorm(mamba*att)*gn_g+gn_b) + x1
__global__ __launch_bounds__(256) void k_final(const float* __restrict__ mamba,
    const float* __restrict__ x1, const float* __restrict__ att,
    const float* __restrict__ gstat, const float* __restrict__ gg,
    const float* __restrict__ gb, float* __restrict__ out){
  const int idx=blockIdx.x*256+threadIdx.x;
  const int c=(idx>>12)&127, b=idx>>19;
  const int grp=(b<<1)+(c>>6);
  float v=mamba[idx]*att[(b<<7)+c];
  float vn=(v-gstat[grp*2])*gstat[grp*2+1]*gg[c]+gb[c];
  out[idx]=silu_(vn)+x1[idx];
}

extern "C" void kernel_launch(void* const* d_in, const int* in_sizes, int n_in,
                              void* d_out, int out_size, void* d_ws, size_t ws_size,
                              hipStream_t stream){
  (void)in_sizes; (void)n_in; (void)out_size; (void)ws_size;
  const float* x        =(const float*)d_in[0];
  const float* convin_w =(const float*)d_in[1];
  const float* convin_b =(const float*)d_in[2];
  const float* ln_g     =(const float*)d_in[3];
  const float* ln_b     =(const float*)d_in[4];
  const float* in_proj_w=(const float*)d_in[5];
  const float* conv_w   =(const float*)d_in[6];
  const float* conv_b   =(const float*)d_in[7];
  const float* x_proj_w =(const float*)d_in[8];
  const float* dt_w     =(const float*)d_in[9];
  const float* dt_b     =(const float*)d_in[10];
  const float* A_logs   =(const float*)d_in[11];
  const float* Ds       =(const float*)d_in[12];
  const float* outnorm_g=(const float*)d_in[13];
  const float* outnorm_b=(const float*)d_in[14];
  const float* out_proj_w=(const float*)d_in[15];
  const float* ca_fc1_w =(const float*)d_in[16];
  const float* ca_fc2_w =(const float*)d_in[17];
  const float* gn_g     =(const float*)d_in[18];
  const float* gn_b     =(const float*)d_in[19];

  float* ws=(float*)d_ws;
  float*          x1     =ws+0;          // [0,1M)      x1ln .. final
  float*          z      =ws+1048576;    // [1M,3M)     inproj .. outnorm
  unsigned short* xmpreb =(unsigned short*)(ws+3145728); // [3M,4M) bf16 2M; inproj .. dwconv
  unsigned short* mlnb   =(unsigned short*)(ws+5242880); // [5M,6M) bf16 2M; x1ln .. inproj
  unsigned short* xflatb =(unsigned short*)(ws+6291456); // [6M,7M) bf16 2M; dwconv .. scanA
  float*          pdt    =ws+8388608;    // [8M,+256K)  proj .. scanC2
  float*          pbc    =ws+8912896;    // [8.5M,9.5M) proj .. scanC2
  unsigned short* Pcb    =(unsigned short*)(ws+10485760); // [10M,12M) bf16 4.2M == Hin
  unsigned short* Heb    =(unsigned short*)(ws+12582912); // [12M,14M) bf16 4.2M
  float*          ysum   =ws+18874368;   // [18M,20M)   memset .. outnorm
  unsigned short* ygb    =(unsigned short*)(ws+3145728); // aliases xmpreb (dead after dwconv)
  float*          mamba  =ws+5242880;    // aliases mlnb (dead after inproj)
  float*          stats  =ws+27262976;
  float*          att    =stats+768;
  float*          gstat  =att+256;

  const dim3 blk(256);
  hipMemsetAsync(ysum, 0, 2097152*sizeof(float), stream);
  k_x1ln   <<<dim3(64,2),   blk,0,stream>>>(x, convin_w, convin_b, ln_g, ln_b, x1, mlnb);
  k_inproj <<<dim3(8,64),   blk,0,stream>>>(mlnb, in_proj_w, xmpreb, z);
  k_dwconv <<<dim3(512),    blk,0,stream>>>(xmpreb, conv_w, conv_b, xflatb);
  k_proj   <<<dim3(256),    blk,0,stream>>>(xflatb, x_proj_w, pdt, pbc);
  k_scanA  <<<dim3(1024),   blk,0,stream>>>(pdt, pbc, xflatb, dt_w, dt_b, A_logs, Ds, Pcb, Heb, ysum);
  k_scanB  <<<dim3(512),    blk,0,stream>>>(Pcb, Heb, Pcb /*Hin*/);
  k_scanC2 <<<dim3(1024),   blk,0,stream>>>(pdt, pbc, dt_w, dt_b, A_logs, Pcb /*Hin*/, ysum);
  k_outnorm<<<dim3(8192),   blk,0,stream>>>(ysum, outnorm_g, outnorm_b, z, ygb);
  k_outproj<<<dim3(256),    blk,0,stream>>>(ygb, out_proj_w, x1, mamba);
  k_stats  <<<dim3(256),    blk,0,stream>>>(mamba, stats);
  k_att    <<<dim3(1),      blk,0,stream>>>(stats, ca_fc1_w, ca_fc2_w, att, gstat);
  k_final  <<<dim3(4096),   blk,0,stream>>>(mamba, x1, att, gstat, gn_g, gn_b, (float*)d_out);
}